// Round 1
// baseline (220.370 us; speedup 1.0000x reference)
//
#include <hip/hip_runtime.h>

// B=64 batches, n=64 nodes/batch, H=128, epg=2048 edges/batch
#define KK 52
#define NKOUT 3328
#define NEG 0.01f

typedef __attribute__((ext_vector_type(8))) __bf16 bf16x8;
typedef __attribute__((ext_vector_type(16))) float floatx16;

__device__ __forceinline__ float lrelu(float v){ return v > 0.f ? v : NEG*v; }

// LDS layout for MFMA chunks: row pitch 40 bf16 (80B); XOR swizzle on 16B chunks
#define SW(r, ko) ((r)*40 + ((ko) ^ ((((r)>>3)&3) << 3)))

__device__ __forceinline__ void split_store8(const float* vv, __bf16* P0, __bf16* P1, __bf16* P2, int addr){
  bf16x8 p1, p2, p3;
  #pragma unroll
  for (int j = 0; j < 8; j++){
    __bf16 b1 = (__bf16)vv[j];
    float r1 = vv[j] - (float)b1;
    __bf16 b2 = (__bf16)r1;
    float r2 = r1 - (float)b2;
    p1[j] = b1; p2[j] = b2; p3[j] = (__bf16)r2;
  }
  *(bf16x8*)(P0 + addr) = p1;
  *(bf16x8*)(P1 + addr) = p2;
  *(bf16x8*)(P2 + addr) = p3;
}

__device__ __forceinline__ void mfma6(const __bf16* A0, const __bf16* A1, const __bf16* A2,
                                      const __bf16* B0, const __bf16* B1, const __bf16* B2,
                                      int aoff, int boff, floatx16* acc){
  bf16x8 a1 = *(const bf16x8*)(A0 + aoff);
  bf16x8 a2 = *(const bf16x8*)(A1 + aoff);
  bf16x8 a3 = *(const bf16x8*)(A2 + aoff);
  bf16x8 b1 = *(const bf16x8*)(B0 + boff);
  bf16x8 b2 = *(const bf16x8*)(B1 + boff);
  bf16x8 b3 = *(const bf16x8*)(B2 + boff);
  floatx16 c = *acc;
  c = __builtin_amdgcn_mfma_f32_32x32x16_bf16(a1,b1,c,0,0,0);
  c = __builtin_amdgcn_mfma_f32_32x32x16_bf16(a1,b2,c,0,0,0);
  c = __builtin_amdgcn_mfma_f32_32x32x16_bf16(a2,b1,c,0,0,0);
  c = __builtin_amdgcn_mfma_f32_32x32x16_bf16(a1,b3,c,0,0,0);
  c = __builtin_amdgcn_mfma_f32_32x32x16_bf16(a3,b1,c,0,0,0);
  c = __builtin_amdgcn_mfma_f32_32x32x16_bf16(a2,b2,c,0,0,0);
  *acc = c;
}

// ---- generic 64x128 MFMA GEMM core (bf16x6 fp32-faithful), fp32 A and B on-the-fly split ----
__device__ __forceinline__ void g_gemm(const float* A0, int ldA,
                                       const float* __restrict__ W0, int ldW, int K,
                                       __bf16* pb, floatx16* oA, floatx16* oB){
  __bf16 *As0 = pb, *As1 = pb+2560, *As2 = pb+5120;
  __bf16 *Bs0 = pb+7680, *Bs1 = pb+12800, *Bs2 = pb+17920;
  int tid = threadIdx.x;
  int sar = tid >> 2, sako = (tid & 3)*8;
  int bn = tid & 127, bk = (tid >> 7)*16;
  int wv_ = tid >> 6, L = tid & 63, m = L & 31, half = L >> 5;
  int rA = 32*(wv_ & 1) + m, rB0 = (wv_ >> 1)*32 + m, rB1 = rB0 + 64;
  const float* arow = A0 + (size_t)sar*ldA;
  floatx16 accA, accB;
  #pragma unroll
  for (int i = 0; i < 16; i++){ accA[i] = 0.f; accB[i] = 0.f; }
  float ra[8], wv[16];
  {
    float4 v0 = *(const float4*)(arow + sako);
    float4 v1 = *(const float4*)(arow + sako + 4);
    ra[0]=v0.x; ra[1]=v0.y; ra[2]=v0.z; ra[3]=v0.w; ra[4]=v1.x; ra[5]=v1.y; ra[6]=v1.z; ra[7]=v1.w;
    #pragma unroll
    for (int j = 0; j < 16; j++) wv[j] = W0[(size_t)(bk + j)*ldW + bn];
  }
  for (int k0 = 0; k0 < K; k0 += 32){
    split_store8(ra, As0, As1, As2, SW(sar, sako));
    split_store8(wv,     Bs0, Bs1, Bs2, SW(bn, bk));
    split_store8(wv + 8, Bs0, Bs1, Bs2, SW(bn, bk + 8));
    __syncthreads();
    int k1 = k0 + 32;
    float ra2[8], wv2[16];
    if (k1 < K){
      float4 v0 = *(const float4*)(arow + k1 + sako);
      float4 v1 = *(const float4*)(arow + k1 + sako + 4);
      ra2[0]=v0.x; ra2[1]=v0.y; ra2[2]=v0.z; ra2[3]=v0.w; ra2[4]=v1.x; ra2[5]=v1.y; ra2[6]=v1.z; ra2[7]=v1.w;
      #pragma unroll
      for (int j = 0; j < 16; j++) wv2[j] = W0[(size_t)(k1 + bk + j)*ldW + bn];
    }
    #pragma unroll
    for (int kg = 0; kg < 2; kg++){
      int ko = kg*16 + half*8;
      mfma6(As0,As1,As2, Bs0,Bs1,Bs2, SW(rA,ko), SW(rB0,ko), &accA);
      mfma6(As0,As1,As2, Bs0,Bs1,Bs2, SW(rA,ko), SW(rB1,ko), &accB);
    }
    __syncthreads();
    if (k1 < K){
      #pragma unroll
      for (int j = 0; j < 8; j++) ra[j] = ra2[j];
      #pragma unroll
      for (int j = 0; j < 16; j++) wv[j] = wv2[j];
    }
  }
  *oA = accA; *oB = accB;
}

// ---- 64x64-tile GEMM: fp32 A (on-the-fly split), pre-split transposed B planes ----
__device__ __forceinline__ void g_gemm64_bp(const float* __restrict__ A0, int ldA,
                                            const __bf16* __restrict__ Bp, int bps, int ldKb, int K,
                                            __bf16* pb, floatx16* oC){
  __bf16 *As0 = pb, *As1 = pb+2560, *As2 = pb+5120;
  __bf16 *Bs0 = pb+7680, *Bs1 = pb+10240, *Bs2 = pb+12800;
  int tid = threadIdx.x;
  int sar = tid >> 2, sako = (tid & 3)*8;
  int bn = tid & 63, bk = (tid >> 6)*8;
  int wv_ = tid >> 6, L = tid & 63, m = L & 31, half = L >> 5;
  int rA = 32*(wv_ & 1) + m, rB = 32*(wv_ >> 1) + m;
  const float* arow = A0 + (size_t)sar*ldA;
  const __bf16* brow = Bp + (size_t)bn*ldKb + bk;
  floatx16 acc;
  #pragma unroll
  for (int i = 0; i < 16; i++) acc[i] = 0.f;
  float ra[8]; bf16x8 rb[3];
  {
    float4 v0 = *(const float4*)(arow + sako);
    float4 v1 = *(const float4*)(arow + sako + 4);
    ra[0]=v0.x; ra[1]=v0.y; ra[2]=v0.z; ra[3]=v0.w; ra[4]=v1.x; ra[5]=v1.y; ra[6]=v1.z; ra[7]=v1.w;
    rb[0] = *(const bf16x8*)(brow);
    rb[1] = *(const bf16x8*)(brow + bps);
    rb[2] = *(const bf16x8*)(brow + 2*bps);
  }
  for (int k0 = 0; k0 < K; k0 += 32){
    split_store8(ra, As0, As1, As2, SW(sar, sako));
    *(bf16x8*)(Bs0 + SW(bn, bk)) = rb[0];
    *(bf16x8*)(Bs1 + SW(bn, bk)) = rb[1];
    *(bf16x8*)(Bs2 + SW(bn, bk)) = rb[2];
    __syncthreads();
    int k1 = k0 + 32;
    float ra2[8]; bf16x8 rb2[3];
    if (k1 < K){
      float4 v0 = *(const float4*)(arow + k1 + sako);
      float4 v1 = *(const float4*)(arow + k1 + sako + 4);
      ra2[0]=v0.x; ra2[1]=v0.y; ra2[2]=v0.z; ra2[3]=v0.w; ra2[4]=v1.x; ra2[5]=v1.y; ra2[6]=v1.z; ra2[7]=v1.w;
      rb2[0] = *(const bf16x8*)(brow + k1);
      rb2[1] = *(const bf16x8*)(brow + bps + k1);
      rb2[2] = *(const bf16x8*)(brow + 2*bps + k1);
    }
    #pragma unroll
    for (int kg = 0; kg < 2; kg++){
      int ko = kg*16 + half*8;
      mfma6(As0,As1,As2, Bs0,Bs1,Bs2, SW(rA,ko), SW(rB,ko), &acc);
    }
    __syncthreads();
    if (k1 < K){
      #pragma unroll
      for (int j = 0; j < 8; j++) ra[j] = ra2[j];
      rb[0]=rb2[0]; rb[1]=rb2[1]; rb[2]=rb2[2];
    }
  }
  *oC = acc;
}

// ---- 64x64-tile GEMM: BOTH sides pre-split planes (pure copy staging) ----
__device__ __forceinline__ void g_gemm64_abp(const __bf16* __restrict__ Ap, int aps, int ldKa,
                                             const __bf16* __restrict__ Bp, int bps, int ldKb, int K,
                                             __bf16* pb, floatx16* oC){
  __bf16 *As0 = pb, *As1 = pb+2560, *As2 = pb+5120;
  __bf16 *Bs0 = pb+7680, *Bs1 = pb+10240, *Bs2 = pb+12800;
  int tid = threadIdx.x;
  int sar = tid >> 2, sako = (tid & 3)*8;
  int bn = tid & 63, bk = (tid >> 6)*8;
  int wv_ = tid >> 6, L = tid & 63, m = L & 31, half = L >> 5;
  int rA = 32*(wv_ & 1) + m, rB = 32*(wv_ >> 1) + m;
  const __bf16* arow = Ap + (size_t)sar*ldKa + sako;
  const __bf16* brow = Bp + (size_t)bn*ldKb + bk;
  floatx16 acc;
  #pragma unroll
  for (int i = 0; i < 16; i++) acc[i] = 0.f;
  bf16x8 ra[3], rb[3];
  {
    ra[0] = *(const bf16x8*)(arow);
    ra[1] = *(const bf16x8*)(arow + aps);
    ra[2] = *(const bf16x8*)(arow + 2*aps);
    rb[0] = *(const bf16x8*)(brow);
    rb[1] = *(const bf16x8*)(brow + bps);
    rb[2] = *(const bf16x8*)(brow + 2*bps);
  }
  for (int k0 = 0; k0 < K; k0 += 32){
    *(bf16x8*)(As0 + SW(sar, sako)) = ra[0];
    *(bf16x8*)(As1 + SW(sar, sako)) = ra[1];
    *(bf16x8*)(As2 + SW(sar, sako)) = ra[2];
    *(bf16x8*)(Bs0 + SW(bn, bk)) = rb[0];
    *(bf16x8*)(Bs1 + SW(bn, bk)) = rb[1];
    *(bf16x8*)(Bs2 + SW(bn, bk)) = rb[2];
    __syncthreads();
    int k1 = k0 + 32;
    bf16x8 ra2[3], rb2[3];
    if (k1 < K){
      ra2[0] = *(const bf16x8*)(arow + k1);
      ra2[1] = *(const bf16x8*)(arow + aps + k1);
      ra2[2] = *(const bf16x8*)(arow + 2*aps + k1);
      rb2[0] = *(const bf16x8*)(brow + k1);
      rb2[1] = *(const bf16x8*)(brow + bps + k1);
      rb2[2] = *(const bf16x8*)(brow + 2*bps + k1);
    }
    #pragma unroll
    for (int kg = 0; kg < 2; kg++){
      int ko = kg*16 + half*8;
      mfma6(As0,As1,As2, Bs0,Bs1,Bs2, SW(rA,ko), SW(rB,ko), &acc);
    }
    __syncthreads();
    if (k1 < K){
      ra[0]=ra2[0]; ra[1]=ra2[1]; ra[2]=ra2[2];
      rb[0]=rb2[0]; rb[1]=rb2[1]; rb[2]=rb2[2];
    }
  }
  *oC = acc;
}

// ---- 64x64-tile W1 GEMM core (K=384, pre-split transposed W1 planes, h=[a,q,a*q] synthesized) ----
__device__ __forceinline__ void g_gemm_h64(const float* __restrict__ arow, const float* __restrict__ qrow,
                                           const __bf16* __restrict__ Bp,
                                           __bf16* pb, floatx16* oC){
  __bf16 *As0 = pb, *As1 = pb+2560, *As2 = pb+5120;
  __bf16 *Bs0 = pb+7680, *Bs1 = pb+10240, *Bs2 = pb+12800;
  int tid = threadIdx.x;
  int sar = tid >> 2, sako = (tid & 3)*8;
  int bn = tid & 63, bk = (tid >> 6)*8;
  int wv_ = tid >> 6, L = tid & 63, m = L & 31, half = L >> 5;
  int rA = 32*(wv_ & 1) + m, rB = 32*(wv_ >> 1) + m;
  const __bf16* brow = Bp + (size_t)bn*384 + bk;
  auto loadA = [&](int k0, float* r){
    int seg = k0 >> 7, kl = (k0 & 127) + sako;
    if (seg == 0){
      float4 a0 = *(const float4*)(arow + kl), a1 = *(const float4*)(arow + kl + 4);
      r[0]=a0.x; r[1]=a0.y; r[2]=a0.z; r[3]=a0.w; r[4]=a1.x; r[5]=a1.y; r[6]=a1.z; r[7]=a1.w;
    } else if (seg == 1){
      float4 q0 = *(const float4*)(qrow + kl), q1 = *(const float4*)(qrow + kl + 4);
      r[0]=q0.x; r[1]=q0.y; r[2]=q0.z; r[3]=q0.w; r[4]=q1.x; r[5]=q1.y; r[6]=q1.z; r[7]=q1.w;
    } else {
      float4 a0 = *(const float4*)(arow + kl), a1 = *(const float4*)(arow + kl + 4);
      float4 q0 = *(const float4*)(qrow + kl), q1 = *(const float4*)(qrow + kl + 4);
      r[0]=a0.x*q0.x; r[1]=a0.y*q0.y; r[2]=a0.z*q0.z; r[3]=a0.w*q0.w;
      r[4]=a1.x*q1.x; r[5]=a1.y*q1.y; r[6]=a1.z*q1.z; r[7]=a1.w*q1.w;
    }
  };
  floatx16 acc;
  #pragma unroll
  for (int i = 0; i < 16; i++) acc[i] = 0.f;
  float ra[8]; bf16x8 rb[3];
  loadA(0, ra);
  rb[0] = *(const bf16x8*)(brow);
  rb[1] = *(const bf16x8*)(brow + 98304);
  rb[2] = *(const bf16x8*)(brow + 196608);
  for (int k0 = 0; k0 < 384; k0 += 32){
    split_store8(ra, As0, As1, As2, SW(sar, sako));
    *(bf16x8*)(Bs0 + SW(bn, bk)) = rb[0];
    *(bf16x8*)(Bs1 + SW(bn, bk)) = rb[1];
    *(bf16x8*)(Bs2 + SW(bn, bk)) = rb[2];
    __syncthreads();
    int k1 = k0 + 32;
    float ra2[8]; bf16x8 rb2[3];
    if (k1 < 384){
      loadA(k1, ra2);
      rb2[0] = *(const bf16x8*)(brow + k1);
      rb2[1] = *(const bf16x8*)(brow + 98304 + k1);
      rb2[2] = *(const bf16x8*)(brow + 196608 + k1);
    }
    #pragma unroll
    for (int kg = 0; kg < 2; kg++){
      int ko = kg*16 + half*8;
      mfma6(As0,As1,As2, Bs0,Bs1,Bs2, SW(rA,ko), SW(rB,ko), &acc);
    }
    __syncthreads();
    if (k1 < 384){
      #pragma unroll
      for (int j = 0; j < 8; j++) ra[j] = ra2[j];
      rb[0]=rb2[0]; rb[1]=rb2[1]; rb[2]=rb2[2];
    }
  }
  *oC = acc;
}

__device__ __forceinline__ void c_write(floatx16 accA, floatx16 accB, float* C0, int ldC, int act){
  int tid = threadIdx.x, wv_ = tid >> 6, L = tid & 63, m = L & 31, half = L >> 5;
  int rB0 = (wv_ >> 1)*32 + m, rB1 = rB0 + 64;
  int row0 = 32*(wv_ & 1) + 4*half;
  #pragma unroll
  for (int reg = 0; reg < 16; reg++){
    int row = row0 + (reg & 3) + 8*(reg >> 2);
    float va = accA[reg], vb = accB[reg];
    if (act){ va = lrelu(va); vb = lrelu(vb); }
    C0[(size_t)row*ldC + rB0] = va;
    C0[(size_t)row*ldC + rB1] = vb;
  }
}

__device__ __forceinline__ void c_write64(floatx16 acc, float* C0, int ldC, int act){
  int tid = threadIdx.x, wv_ = tid >> 6, L = tid & 63, m = L & 31, half = L >> 5;
  int col = 32*(wv_ >> 1) + m;
  int row0 = 32*(wv_ & 1) + 4*half;
  #pragma unroll
  for (int reg = 0; reg < 16; reg++){
    int row = row0 + (reg & 3) + 8*(reg >> 2);
    float v = acc[reg];
    if (act) v = lrelu(v);
    C0[(size_t)row*ldC + col] = v;
  }
}

// epilogue: lrelu + split into 3 bf16 planes (plane stride 16384 = 64x256)
__device__ __forceinline__ void c_write64_planes(floatx16 acc, __bf16* P){
  int tid = threadIdx.x, wv_ = tid >> 6, L = tid & 63, m = L & 31, half = L >> 5;
  int col = 32*(wv_ >> 1) + m;
  int row0 = 32*(wv_ & 1) + 4*half;
  #pragma unroll
  for (int reg = 0; reg < 16; reg++){
    int row = row0 + (reg & 3) + 8*(reg >> 2);
    float v = lrelu(acc[reg]);
    __bf16 b1 = (__bf16)v;
    float r1 = v - (float)b1;
    __bf16 b2 = (__bf16)r1;
    __bf16 b3 = (__bf16)(r1 - (float)b2);
    int o = row*256 + col;
    P[o] = b1; P[16384 + o] = b2; P[32768 + o] = b3;
  }
}

// ---- double hop (A^T twice), A in LDS; src either global rows (ld128) or LDS (ldV); dst ld128 ----
__device__ __forceinline__ void hop2_run(const float* A, const float* VfullL, int ldV,
                                         const float* srcG, float* dstG, int dstOff,
                                         float* Vt, float* Tt, int fbeg, int fend){
  int tid = threadIdx.x;
  int tc = (tid & 31)*2, tf = (tid >> 5)*4;
  for (int f0 = fbeg; f0 < fend; f0 += 32){
    if (!VfullL){
      for (int o = tid; o < 2048; o += 256){
        int r = o >> 5, f = o & 31;
        Vt[o] = srcG[r*128 + f0 + f];
      }
      __syncthreads();
    }
    float a00,a01,a02,a03,a10,a11,a12,a13;
    a00=a01=a02=a03=a10=a11=a12=a13=0.f;
    for (int r = 0; r < 64; r++){
      float x0 = A[r*64 + tc], x1 = A[r*64 + tc + 1];
      float4 v4 = VfullL ? *(const float4*)&VfullL[r*ldV + f0 + tf]
                         : *(const float4*)&Vt[r*32 + tf];
      a00 += x0*v4.x; a01 += x0*v4.y; a02 += x0*v4.z; a03 += x0*v4.w;
      a10 += x1*v4.x; a11 += x1*v4.y; a12 += x1*v4.z; a13 += x1*v4.w;
    }
    *(float4*)&Tt[tc*32 + tf]     = make_float4(a00,a01,a02,a03);
    *(float4*)&Tt[(tc+1)*32 + tf] = make_float4(a10,a11,a12,a13);
    __syncthreads();
    a00=a01=a02=a03=a10=a11=a12=a13=0.f;
    for (int r = 0; r < 64; r++){
      float x0 = A[r*64 + tc], x1 = A[r*64 + tc + 1];
      float4 v4 = *(const float4*)&Tt[r*32 + tf];
      a00 += x0*v4.x; a01 += x0*v4.y; a02 += x0*v4.z; a03 += x0*v4.w;
      a10 += x1*v4.x; a11 += x1*v4.y; a12 += x1*v4.z; a13 += x1*v4.w;
    }
    *(float4*)(dstG + tc*128 + dstOff + f0 + tf)     = make_float4(a00,a01,a02,a03);
    *(float4*)(dstG + (tc+1)*128 + dstOff + f0 + tf) = make_float4(a10,a11,a12,a13);
    __syncthreads();
  }
}

// generic split+transpose of a 64x64 fp32 tile into 3 transposed bf16 planes via LDS
// (caller computes v per (kk,cc); here we provide the store helper)
__device__ __forceinline__ void split_t_lds(float v, __bf16* Ls, int idx){
  __bf16 b1 = (__bf16)v;
  float r1 = v - (float)b1;
  __bf16 b2 = (__bf16)r1;
  __bf16 b3 = (__bf16)(r1 - (float)b2);
  Ls[idx] = b1; Ls[4224 + idx] = b2; Ls[8448 + idx] = b3;
}

// ===== K1: build+hop2 f-split (blk<128) || Wk-f GEMM (128..255) || W1 fold presplit (256..351)
//          || W2 presplit (352..383) || Wkg presplit (384..391)
//          || A2 zero (392..3095) || xl = x @ linW (3096..3223) =====
__global__ __launch_bounds__(256) void k_p0(const int* __restrict__ ei, const float* __restrict__ ew,
                                            const float* __restrict__ x, const float* __restrict__ Wk,
                                            const float* __restrict__ W1, const float* __restrict__ W2,
                                            const float* __restrict__ linW,
                                            float* A_g, float* M_g, float* xq, float* a_buf,
                                            __bf16* W1fp, __bf16* W2p, __bf16* Wkgp,
                                            float* xl0, float* xl1, float* outA2){
  __shared__ __align__(16) char POOL[57856];
  float* pf = (float*)POOL;
  __bf16* pb = (__bf16*)POOL;
  int blk = blockIdx.x, tid = threadIdx.x;
  if (blk < 128){
    int b = blk >> 1, fh = blk & 1;
    float* Ws = pf; float* Mc = pf + 4096; float* dv = pf + 8192;
    for (int i = tid; i < 4096; i += 256){ Ws[i] = 0.f; Mc[i] = 0.f; }
    __syncthreads();
    const int* r0 = ei + b*2048;
    const int* c0 = ei + 64*2048 + b*2048;
    const float* w0 = ew + b*2048;
    int base = b*64;
    for (int e = tid; e < 2048; e += 256){
      int r = r0[e] - base, c = c0[e] - base;
      atomicAdd(&Ws[r*64 + c], w0[e]);
      atomicAdd(&Mc[r*64 + c], 1.f);
    }
    if (tid < 64){ atomicAdd(&Ws[tid*65], 1.f); atomicAdd(&Mc[tid*65], 1.f); }
    __syncthreads();
    if (tid < 64){
      float d = 0.f;
      for (int r = 0; r < 64; r++) d += Ws[r*64 + tid];
      dv[tid] = d > 0.f ? rsqrtf(fmaxf(d, 1e-12f)) : 0.f;
    }
    __syncthreads();
    for (int i = tid; i < 4096; i += 256){
      int r = i >> 6, c = i & 63;
      float a = dv[r]*Ws[i]*dv[c];
      Ws[i] = a;
      if (fh == 0){
        A_g[b*4096 + i] = a;
        M_g[b*4096 + i] = Mc[i];
      }
    }
    __syncthreads();
    hop2_run(Ws, nullptr, 0, x + (size_t)b*8192, xq + (size_t)b*8192, 0, pf + 8256, pf + 10304,
             fh*64, fh*64 + 64);
  } else if (blk < 256){
    int idx = blk - 128, z = idx >> 6, b = idx & 63;
    floatx16 cA, cB;
    g_gemm(x + (size_t)b*8192, 128, Wk + (size_t)z*16384, 128, 128, pb, &cA, &cB);
    c_write(cA, cB, a_buf + (size_t)z*524288 + (size_t)b*8192, 128, 0);
  } else if (blk < 352){
    // W1 fold + split + transpose -> W1fp[z][plane][256 n][384 k] bf16
    __bf16* Ls = (__bf16*)POOL;
    int t = blk - 256, z = t/24, tt = t%24, k0 = (tt >> 2)*64, c0 = (tt & 3)*64;
    const float* Wz = W1 + (size_t)z*131072;
    for (int i = tid; i < 4096; i += 256){
      int kk = i >> 6, cc = i & 63, kr = k0 + kk, c = c0 + cc;
      float v;
      if (kr < 128)       v = Wz[kr*256 + c] + Wz[(kr + 256)*256 + c];
      else if (kr < 256)  v = Wz[kr*256 + c] - Wz[(kr + 128)*256 + c];
      else                v = Wz[(kr + 128)*256 + c];
      split_t_lds(v, Ls, cc*66 + kk);
    }
    __syncthreads();
    __bf16* outp = W1fp + (size_t)z*294912;
    for (int i = tid; i < 4096; i += 256){
      int cc = i >> 6, kk = i & 63;
      int o = (c0 + cc)*384 + k0 + kk;
      int li = cc*66 + kk;
      outp[o] = Ls[li];
      outp[98304 + o] = Ls[4224 + li];
      outp[196608 + o] = Ls[8448 + li];
    }
  } else if (blk < 384){
    // W2 split + transpose -> W2p[z][plane][128 n][256 k]
    __bf16* Ls = (__bf16*)POOL;
    int t = blk - 352, z = t >> 3, tt = t & 7, k0 = (tt >> 1)*64, c0 = (tt & 1)*64;
    const float* Wz = W2 + (size_t)z*32768;
    for (int i = tid; i < 4096; i += 256){
      int kk = i >> 6, cc = i & 63;
      split_t_lds(Wz[(k0 + kk)*128 + c0 + cc], Ls, cc*66 + kk);
    }
    __syncthreads();
    __bf16* outp = W2p + (size_t)z*98304;
    for (int i = tid; i < 4096; i += 256){
      int cc = i >> 6, kk = i & 63;
      int o = (c0 + cc)*256 + k0 + kk;
      int li = cc*66 + kk;
      outp[o] = Ls[li];
      outp[32768 + o] = Ls[4224 + li];
      outp[65536 + o] = Ls[8448 + li];
    }
  } else if (blk < 392){
    // Wk heads 2,3 split + transpose -> Wkgp[z][plane][128 n][128 k]
    __bf16* Ls = (__bf16*)POOL;
    int t = blk - 384, z = t >> 2, tt = t & 3, k0 = (tt >> 1)*64, c0 = (tt & 1)*64;
    const float* Wz = Wk + (size_t)(2 + z)*16384;
    for (int i = tid; i < 4096; i += 256){
      int kk = i >> 6, cc = i & 63;
      split_t_lds(Wz[(k0 + kk)*128 + c0 + cc], Ls, cc*66 + kk);
    }
    __syncthreads();
    __bf16* outp = Wkgp + (size_t)z*49152;
    for (int i = tid; i < 4096; i += 256){
      int cc = i >> 6, kk = i & 63;
      int o = (c0 + cc)*128 + k0 + kk;
      int li = cc*66 + kk;
      outp[o] = Ls[li];
      outp[16384 + o] = Ls[4224 + li];
      outp[32768 + o] = Ls[8448 + li];
    }
  } else if (blk < 3096){
    // zero-fill full A2 region (44.3 MB); nonzero blocks overwritten later by k_A2c
    float4* p = (float4*)outA2;
    int base = (blk - 392)*1024 + tid;
    #pragma unroll
    for (int i = 0; i < 4; i++) p[base + i*256] = make_float4(0.f,0.f,0.f,0.f);
  } else {
    // xl_h = x @ linW_h (2 heads x 64 batches)
    int idx = blk - 3096, z = idx >> 6, b = idx & 63;
    floatx16 cA, cB;
    g_gemm(x + (size_t)b*8192, 128, linW + (size_t)z*16384, 128, 128, pb, &cA, &cB);
    c_write(cA, cB, (z ? xl1 : xl0) + (size_t)b*8192, 128, 0);
  }
}

// ===== K2: W1 fold GEMM (512 blocks: b,z,nq) — 64x64 tiles, presplit B, plane-split h1 out =====
__global__ __launch_bounds__(256) void k_h1(const float* __restrict__ a_buf, const float* __restrict__ q0,
                                            const float* __restrict__ tgt, const __bf16* __restrict__ W1fp,
                                            __bf16* h1p){
  __shared__ __align__(16) char POOL[30720];
  __bf16* pb = (__bf16*)POOL;
  int blk = blockIdx.x, tid = threadIdx.x;
  int b = blk >> 3, z = (blk >> 2) & 1, nq = blk & 3;
  int sar = tid >> 2;
  const float* arow = a_buf + (size_t)z*524288 + ((size_t)b*64 + sar)*128;
  const float* qrow = z ? (tgt + (size_t)b*128) : (q0 + ((size_t)b*64 + sar)*128);
  floatx16 c;
  g_gemm_h64(arow, qrow, W1fp + (size_t)z*294912 + (size_t)nq*64*384, pb, &c);
  c_write64_planes(c, h1p + (size_t)(z*64 + b)*3*16384 + nq*64);
}

// ===== K3: W2 partial-logit GEMM (256 blocks: b,z,nh) — both operands pre-split =====
__global__ __launch_bounds__(256) void k_w2p(const __bf16* __restrict__ h1p, const __bf16* __restrict__ W2p,
                                             const float* __restrict__ W3, float* __restrict__ lp){
  __shared__ __align__(16) char POOL[30720];
  __shared__ float lgp[128];
  __bf16* pb = (__bf16*)POOL;
  int blk = blockIdx.x, tid = threadIdx.x;
  int b = blk >> 2, z = (blk >> 1) & 1, nh = blk & 1;
  floatx16 c;
  g_gemm64_abp(h1p + (size_t)(z*64 + b)*3*16384, 16384, 256,
               W2p + (size_t)z*98304 + (size_t)nh*64*256, 32768, 256, 256, pb, &c);
  int wv_ = tid >> 6, L = tid & 63, m = L & 31, half = L >> 5;
  int col = 32*(wv_ >> 1) + m;
  float w = W3[z*128 + nh*64 + col];
  float v[16];
  #pragma unroll
  for (int reg = 0; reg < 16; reg++) v[reg] = lrelu(c[reg])*w;
  #pragma unroll
  for (int off = 1; off < 32; off <<= 1)
    #pragma unroll
    for (int reg = 0; reg < 16; reg++) v[reg] += __shfl_xor(v[reg], off);
  if (m == 0){
    #pragma unroll
    for (int reg = 0; reg < 16; reg++) lgp[wv_*32 + half*16 + reg] = v[reg];
  }
  __syncthreads();
  if (tid < 64){
    int row = tid, rh = row >> 5, rem = row & 31;
    int hf = (rem >> 2) & 1, rg = (rem & 3) + 4*(rem >> 3);
    float p = lgp[rh*32 + hf*16 + rg] + lgp[(rh + 2)*32 + hf*16 + rg];
    lp[(z*2 + nh)*4096 + b*64 + row] = p;
  }
}

// ===== K4: edge softmax + S + y=Ew^T xl + x_c + hop2, f-split (128 blocks: b, fh) =====
__global__ __launch_bounds__(256) void k_edgehop(const float* __restrict__ M_g, const float* __restrict__ lp,
                                                 const float* __restrict__ x, const float* __restrict__ xl0g,
                                                 const float* __restrict__ xl1g, const float* __restrict__ A_g,
                                                 float* S_g, float* xcb, float* xq2){
  __shared__ __align__(16) float Mc[4096];     // multiplicity -> Ew
  __shared__ __align__(16) float xh[4096];     // x half -> x_c half (in-place)
  __shared__ __align__(16) float xl0h[4096];
  __shared__ __align__(16) float xl1h[4096];
  __shared__ __align__(16) float Ab[4096];
  __shared__ __align__(16) float Tt[2048];
  __shared__ float f1s[64], f2s[64];
  int blk = blockIdx.x, b = blk >> 1, fh = blk & 1, tid = threadIdx.x;
  int foff = fh*64;
  for (int i = tid; i < 4096; i += 256) Mc[i] = M_g[b*4096 + i];
  for (int o = tid*4; o < 4096; o += 1024){
    int r = o >> 6, f = o & 63;
    *(float4*)&xh[o]   = *(const float4*)(x    + (size_t)b*8192 + r*128 + foff + f);
    *(float4*)&xl0h[o] = *(const float4*)(xl0g + (size_t)b*8192 + r*128 + foff + f);
    *(float4*)&xl1h[o] = *(const float4*)(xl1g + (size_t)b*8192 + r*128 + foff + f);
  }
  if (tid < 128){
    int z = tid >> 6, r = tid & 63;
    float d = lp[(z*2)*4096 + b*64 + r] + lp[(z*2 + 1)*4096 + b*64 + r];
    float l = lrelu(d);
    float mx = l;
    #pragma unroll
    for (int off = 32; off; off >>= 1) mx = fmaxf(mx, __shfl_xor(mx, off));
    float e = expf(l - mx);
    float s = e;
    #pragma unroll
    for (int off = 32; off; off >>= 1) s += __shfl_xor(s, off);
    (z ? f2s : f1s)[r] = e/s;
  }
  __syncthreads();
  {
    int c = tid >> 2, sub = tid & 3;
    float m = -1e30f;
    for (int r = sub; r < 64; r += 4)
      if (Mc[r*64 + c] > 0.f) m = fmaxf(m, lrelu(f1s[c] + f2s[r]));
    m = fmaxf(m, __shfl_xor(m, 1));
    m = fmaxf(m, __shfl_xor(m, 2));
    float s = 0.f;
    for (int r = sub; r < 64; r += 4){
      float mc = Mc[r*64 + c];
      if (mc > 0.f) s += mc*expf(lrelu(f1s[c] + f2s[r]) - m);
    }
    s += __shfl_xor(s, 1);
    s += __shfl_xor(s, 2);
    for (int r = sub; r < 64; r += 4){
      float mc = Mc[r*64 + c];
      float v = 0.f;
      if (mc > 0.f) v = mc*expf(lrelu(f1s[c] + f2s[r]) - m)/s;
      Mc[r*64 + c] = v;
    }
  }
  __syncthreads();
  if (fh == 0)
    for (int i = tid; i < 4096; i += 256) S_g[b*4096 + i] = Mc[i];
  // y_h[c][f] = sum_r Ew[r][c] * xl_h[r][f]; then x_c in-place into xh
  {
    int tc = (tid & 15)*4, tf = (tid >> 4)*4;
    float a0[4][4], a1[4][4];
    #pragma unroll
    for (int i = 0; i < 4; i++)
      #pragma unroll
      for (int j = 0; j < 4; j++){ a0[i][j] = 0.f; a1[i][j] = 0.f; }
    for (int r = 0; r < 64; r++){
      float4 e4 = *(const float4*)&Mc[r*64 + tc];
      float4 p0 = *(const float4*)&xl0h[r*64 + tf];
      float4 p1 = *(const float4*)&xl1h[r*64 + tf];
      float e_[4] = {e4.x,e4.y,e4.z,e4.w};
      float p0_[4] = {p0.x,p0.y,p0.z,p0.w};
      float p1_[4] = {p1.x,p1.y,p1.z,p1.w};
      #pragma unroll
      for (int ci = 0; ci < 4; ci++)
        #pragma unroll
        for (int fj = 0; fj < 4; fj++){
          a0[ci][fj] += e_[ci]*p0_[fj];
          a1[ci][fj] += e_[ci]*p1_[fj];
        }
    }
    __syncthreads();
    #pragma unroll
    for (int ci = 0; ci < 4; ci++){
      int c = tc + ci;
      float4 xv = *(const float4*)&xh[c*64 + tf];
      float4 o;
      o.x = 0.5f*(lrelu(xv.x + a0[ci][0]) + lrelu(xv.x + a1[ci][0]));
      o.y = 0.5f*(lrelu(xv.y + a0[ci][1]) + lrelu(xv.y + a1[ci][1]));
      o.z = 0.5f*(lrelu(xv.z + a0[ci][2]) + lrelu(xv.z + a1[ci][2]));
      o.w = 0.5f*(lrelu(xv.w + a0[ci][3]) + lrelu(xv.w + a1[ci][3]));
      *(float4*)&xh[c*64 + tf] = o;
      *(float4*)(xcb + (size_t)b*8192 + c*128 + foff + tf) = o;
    }
  }
  for (int i = tid*4; i < 4096; i += 1024)
    *(float4*)&Ab[i] = *(const float4*)(A_g + b*4096 + i);
  __syncthreads();
  hop2_run(Ab, xh, 64, nullptr, xq2 + (size_t)b*8192, foff, Tt, Tt, 0, 64);
}

// ===== K5: Wk pair g (256 blocks: b,z,nh) — 64x64 tiles, presplit B =====
__global__ __launch_bounds__(256) void k_wkg(const float* __restrict__ xcb, const __bf16* __restrict__ Wkgp,
                                             float* a_buf){
  __shared__ __align__(16) char POOL[30720];
  __bf16* pb = (__bf16*)POOL;
  int blk = blockIdx.x;
  int b = blk >> 2, z = (blk >> 1) & 1, nh = blk & 1;
  floatx16 c;
  g_gemm64_bp(xcb + (size_t)b*8192, 128,
              Wkgp + (size_t)z*49152 + (size_t)nh*64*128, 16384, 128, 128, pb, &c);
  c_write64(c, a_buf + (size_t)z*524288 + (size_t)b*8192 + nh*64, 128, 0);
}

// ===== K6: pool (softmaxes from lp + bitonic top-52 + x_out) + direct A2 block writes (64 blocks) =====
__global__ __launch_bounds__(256) void k_A2c(const float* __restrict__ lp, const float* __restrict__ x,
                                             const float* __restrict__ A_g, const float* __restrict__ S_g,
                                             float* outA2, float* outX, float* outB, float* outP){
  __shared__ __align__(16) float At[64*68];
  __shared__ __align__(16) float Sp[64*56];
  __shared__ __align__(16) float Tq[64*56];
  __shared__ int pi[64];
  __shared__ float pv[64];
  int b = blockIdx.x, tid = threadIdx.x;
  if (tid < 64){
    int lane = tid;
    float f[2];
    #pragma unroll
    for (int z = 0; z < 2; z++){
      float d = lp[(z*2)*4096 + b*64 + lane] + lp[(z*2 + 1)*4096 + b*64 + lane];
      float l = lrelu(d);
      float mx = l;
      #pragma unroll
      for (int off = 32; off; off >>= 1) mx = fmaxf(mx, __shfl_xor(mx, off));
      float e = expf(l - mx);
      float sm = e;
      #pragma unroll
      for (int off = 32; off; off >>= 1) sm += __shfl_xor(sm, off);
      f[z] = e/sm;
    }
    float l = f[0] + f[1];
    float m = l;
    #pragma unroll
    for (int off = 32; off; off >>= 1) m = fmaxf(m, __shfl_xor(m, off));
    float e = expf(l - m);
    float sm = e;
    #pragma unroll
    for (int off = 32; off; off >>= 1) sm += __shfl_xor(sm, off);
    float v = e/sm;
    int idx = lane;
    #pragma unroll
    for (int k = 2; k <= 64; k <<= 1){
      #pragma unroll
      for (int j = k >> 1; j > 0; j >>= 1){
        float ov = __shfl_xor(v, j);
        int   oi = __shfl_xor(idx, j);
        bool ascBlock = (lane & k) == 0;
        bool iAmLow   = (lane & j) == 0;
        bool otherPrec = (ov > v) || (ov == v && oi < idx);
        bool take = (ascBlock == iAmLow) ? otherPrec : !otherPrec;
        if (take){ v = ov; idx = oi; }
      }
    }
    pi[lane] = idx; pv[lane] = v;
    if (lane < KK){
      outB[b*KK + lane] = (float)b;
      outP[b*KK + lane] = (float)(b*64 + idx);
    }
  }
  __syncthreads();
  for (int o = tid*4; o < KK*128; o += 1024){
    int j = o >> 7, f = o & 127;
    float4 xv = *(const float4*)(x + ((size_t)b*64 + pi[j])*128 + f);
    float sv = pv[j];
    *(float4*)(outX + (size_t)b*KK*128 + o) = make_float4(xv.x*sv, xv.y*sv, xv.z*sv, xv.w*sv);
  }
  for (int idx = tid; idx < 4096; idx += 256){
    int i = idx >> 6, k = idx & 63;
    At[k*68 + i] = A_g[b*4096 + idx];
  }
  for (int idx = tid; idx < 4096; idx += 256){
    int k = idx >> 6, t = idx & 63;
    if (t < 56) Sp[k*56 + t] = (t < KK) ? S_g[b*4096 + k*64 + pi[t]] : 0.f;
  }
  __syncthreads();
  if (tid < 224){
    int i0 = (tid/14)*4, t0 = (tid % 14)*4;
    float acc[4][4];
    #pragma unroll
    for (int a = 0; a < 4; a++)
      #pragma unroll
      for (int c = 0; c < 4; c++) acc[a][c] = 0.f;
    for (int k = 0; k < 64; k++){
      float4 a4 = *(const float4*)&At[k*68 + i0];
      float4 s4 = *(const float4*)&Sp[k*56 + t0];
      float a_[4] = {a4.x,a4.y,a4.z,a4.w};
      float s_[4] = {s4.x,s4.y,s4.z,s4.w};
      #pragma unroll
      for (int ii = 0; ii < 4; ii++)
        #pragma unroll
        for (int tt = 0; tt < 4; tt++) acc[ii][tt] += a_[ii]*s_[tt];
    }
    #pragma unroll
    for (int ii = 0; ii < 4; ii++)
      *(float4*)&Tq[(i0+ii)*56 + t0] = make_float4(acc[ii][0],acc[ii][1],acc[ii][2],acc[ii][3]);
  }
  __syncthreads();
  if (tid < 169){
    int a0 = (tid/13)*4, t0 = (tid % 13)*4;
    float acc[4][4];
    #pragma unroll
    for (int a = 0; a < 4; a++)
      #pragma unroll
      for (int c = 0; c < 4; c++) acc[a][c] = 0.f;
    for (int i = 0; i < 64; i++){
      float4 s4 = *(const float4*)&Sp[i*56 + a0];
      float4 t4 = *(const float4*)&Tq[i*56 + t0];
      float s_[4] = {s4.x,s4.y,s4.z,s4.w};
      float t_[4] = {t4.x,t4.y,t4.z,t4.w};
      #pragma unroll
      for (int aa = 0; aa < 4; aa++)
        #pragma unroll
        for (int tt = 0; tt < 4; tt++) acc[aa][tt] += s_[aa]*t_[tt];
    }
    #pragma unroll
    for (int aa = 0; aa < 4; aa++){
      int a = a0 + aa;
      float4 o;
      o.x = (a == t0    ) ? 1.f : acc[aa][0];
      o.y = (a == t0 + 1) ? 1.f : acc[aa][1];
      o.z = (a == t0 + 2) ? 1.f : acc[aa][2];
      o.w = (a == t0 + 3) ? 1.f : acc[aa][3];
      *(float4*)(outA2 + (size_t)(b*KK + a)*NKOUT + b*KK + t0) = o;
    }
  }
}

extern "C" void kernel_launch(void* const* d_in, const int* in_sizes, int n_in,
                              void* d_out, int out_size, void* d_ws, size_t ws_size,
                              hipStream_t stream){
  const float* x    = (const float*)d_in[0];
  const int*   ei   = (const int*)d_in[1];
  const float* ew   = (const float*)d_in[2];
  const float* tgt  = (const float*)d_in[3];
  const float* Wk   = (const float*)d_in[5];
  const float* W1   = (const float*)d_in[6];
  const float* W2   = (const float*)d_in[7];
  const float* W3   = (const float*)d_in[8];
  const float* linW = (const float*)d_in[9];
  float* out = (float*)d_out;

  float* wf   = (float*)d_ws;
  float* A_g  = wf;
  float* M_g  = wf + 262144;
  float* S_g  = wf + 524288;
  float* xq   = wf + 786432;
  float* xq2  = wf + 1310720;
  float* xl0  = wf + 1835008;
  float* xcb  = wf + 2359296;
  float* a_buf= wf + 2883584;              // 2 x 524288
  float* lp   = wf + 3932160;              // 4 x 4096 partial logits
  float* xl1  = wf + 3948544;              // 524288
  __bf16* W1fp = (__bf16*)(wf + 4472832);  // 4 z x 3 planes x 256 n x 384 k
  __bf16* W2p  = (__bf16*)(wf + 5062656);  // 4 z x 3 planes x 128 n x 256 k
  __bf16* Wkgp = (__bf16*)(wf + 5259264);  // 2 z x 3 planes x 128 n x 128 k
  __bf16* h1p  = (__bf16*)(wf + 5308416);  // 2 z x 64 b x 3 planes x 64 x 256

  float* outX  = out;
  float* outA2 = out + 425984;
  float* outB  = out + 425984 + 11075584;
  float* outP  = outB + NKOUT;

  // pair f (+ weight pre-split/transpose + A2 zero-fill + xl precompute in spare blocks)
  k_p0<<<dim3(3224), dim3(256), 0, stream>>>(ei, ew, x, Wk, W1, W2, linW, A_g, M_g, xq, a_buf,
                                             W1fp, W2p, Wkgp, xl0, xl1, outA2);
  k_h1<<<dim3(512), dim3(256), 0, stream>>>(a_buf, xq, tgt, W1fp, h1p);
  k_w2p<<<dim3(256), dim3(256), 0, stream>>>(h1p, W2p, W3, lp);
  // fused edge softmax + S + y=Ew^T xl + x_c + hop2 (f-split, 128 blocks)
  k_edgehop<<<dim3(128), dim3(256), 0, stream>>>(M_g, lp, x, xl0, xl1, A_g, S_g, xcb, xq2);
  // pair g
  k_wkg<<<dim3(256), dim3(256), 0, stream>>>(xcb, Wkgp, a_buf);
  k_h1<<<dim3(512), dim3(256), 0, stream>>>(a_buf, xq2, tgt, W1fp + 2*294912, h1p);
  k_w2p<<<dim3(256), dim3(256), 0, stream>>>(h1p, W2p + 2*98304, W3 + 2*128, lp);
  // pool + direct A2 block writes
  k_A2c<<<dim3(64), dim3(256), 0, stream>>>(lp, x, A_g, S_g, outA2, outX, outB, outP);
}

// Round 2
// 214.711 us; speedup vs baseline: 1.0264x; 1.0264x over previous
//
#include <hip/hip_runtime.h>

// B=64 batches, n=64 nodes/batch, H=128, epg=2048 edges/batch
#define KK 52
#define NKOUT 3328
#define NEG 0.01f

typedef __attribute__((ext_vector_type(8))) __bf16 bf16x8;
typedef __attribute__((ext_vector_type(16))) float floatx16;

__device__ __forceinline__ float lrelu(float v){ return v > 0.f ? v : NEG*v; }

// LDS layout for MFMA chunks: row pitch 40 bf16 (80B); XOR swizzle on 16B chunks
#define SW(r, ko) ((r)*40 + ((ko) ^ ((((r)>>3)&3) << 3)))

__device__ __forceinline__ void split_store8(const float* vv, __bf16* P0, __bf16* P1, __bf16* P2, int addr){
  bf16x8 p1, p2, p3;
  #pragma unroll
  for (int j = 0; j < 8; j++){
    __bf16 b1 = (__bf16)vv[j];
    float r1 = vv[j] - (float)b1;
    __bf16 b2 = (__bf16)r1;
    float r2 = r1 - (float)b2;
    p1[j] = b1; p2[j] = b2; p3[j] = (__bf16)r2;
  }
  *(bf16x8*)(P0 + addr) = p1;
  *(bf16x8*)(P1 + addr) = p2;
  *(bf16x8*)(P2 + addr) = p3;
}

__device__ __forceinline__ void mfma6(const __bf16* A0, const __bf16* A1, const __bf16* A2,
                                      const __bf16* B0, const __bf16* B1, const __bf16* B2,
                                      int aoff, int boff, floatx16* acc){
  bf16x8 a1 = *(const bf16x8*)(A0 + aoff);
  bf16x8 a2 = *(const bf16x8*)(A1 + aoff);
  bf16x8 a3 = *(const bf16x8*)(A2 + aoff);
  bf16x8 b1 = *(const bf16x8*)(B0 + boff);
  bf16x8 b2 = *(const bf16x8*)(B1 + boff);
  bf16x8 b3 = *(const bf16x8*)(B2 + boff);
  floatx16 c = *acc;
  c = __builtin_amdgcn_mfma_f32_32x32x16_bf16(a1,b1,c,0,0,0);
  c = __builtin_amdgcn_mfma_f32_32x32x16_bf16(a1,b2,c,0,0,0);
  c = __builtin_amdgcn_mfma_f32_32x32x16_bf16(a2,b1,c,0,0,0);
  c = __builtin_amdgcn_mfma_f32_32x32x16_bf16(a1,b3,c,0,0,0);
  c = __builtin_amdgcn_mfma_f32_32x32x16_bf16(a3,b1,c,0,0,0);
  c = __builtin_amdgcn_mfma_f32_32x32x16_bf16(a2,b2,c,0,0,0);
  *acc = c;
}

// ---- generic 64x128 MFMA GEMM core (bf16x6 fp32-faithful), fp32 A and B on-the-fly split ----
__device__ __forceinline__ void g_gemm(const float* A0, int ldA,
                                       const float* __restrict__ W0, int ldW, int K,
                                       __bf16* pb, floatx16* oA, floatx16* oB){
  __bf16 *As0 = pb, *As1 = pb+2560, *As2 = pb+5120;
  __bf16 *Bs0 = pb+7680, *Bs1 = pb+12800, *Bs2 = pb+17920;
  int tid = threadIdx.x;
  int sar = tid >> 2, sako = (tid & 3)*8;
  int bn = tid & 127, bk = (tid >> 7)*16;
  int wv_ = tid >> 6, L = tid & 63, m = L & 31, half = L >> 5;
  int rA = 32*(wv_ & 1) + m, rB0 = (wv_ >> 1)*32 + m, rB1 = rB0 + 64;
  const float* arow = A0 + (size_t)sar*ldA;
  floatx16 accA, accB;
  #pragma unroll
  for (int i = 0; i < 16; i++){ accA[i] = 0.f; accB[i] = 0.f; }
  float ra[8], wv[16];
  {
    float4 v0 = *(const float4*)(arow + sako);
    float4 v1 = *(const float4*)(arow + sako + 4);
    ra[0]=v0.x; ra[1]=v0.y; ra[2]=v0.z; ra[3]=v0.w; ra[4]=v1.x; ra[5]=v1.y; ra[6]=v1.z; ra[7]=v1.w;
    #pragma unroll
    for (int j = 0; j < 16; j++) wv[j] = W0[(size_t)(bk + j)*ldW + bn];
  }
  for (int k0 = 0; k0 < K; k0 += 32){
    split_store8(ra, As0, As1, As2, SW(sar, sako));
    split_store8(wv,     Bs0, Bs1, Bs2, SW(bn, bk));
    split_store8(wv + 8, Bs0, Bs1, Bs2, SW(bn, bk + 8));
    __syncthreads();
    int k1 = k0 + 32;
    float ra2[8], wv2[16];
    if (k1 < K){
      float4 v0 = *(const float4*)(arow + k1 + sako);
      float4 v1 = *(const float4*)(arow + k1 + sako + 4);
      ra2[0]=v0.x; ra2[1]=v0.y; ra2[2]=v0.z; ra2[3]=v0.w; ra2[4]=v1.x; ra2[5]=v1.y; ra2[6]=v1.z; ra2[7]=v1.w;
      #pragma unroll
      for (int j = 0; j < 16; j++) wv2[j] = W0[(size_t)(k1 + bk + j)*ldW + bn];
    }
    #pragma unroll
    for (int kg = 0; kg < 2; kg++){
      int ko = kg*16 + half*8;
      mfma6(As0,As1,As2, Bs0,Bs1,Bs2, SW(rA,ko), SW(rB0,ko), &accA);
      mfma6(As0,As1,As2, Bs0,Bs1,Bs2, SW(rA,ko), SW(rB1,ko), &accB);
    }
    __syncthreads();
    if (k1 < K){
      #pragma unroll
      for (int j = 0; j < 8; j++) ra[j] = ra2[j];
      #pragma unroll
      for (int j = 0; j < 16; j++) wv[j] = wv2[j];
    }
  }
  *oA = accA; *oB = accB;
}

// ---- 64x64-tile GEMM: fp32 A (on-the-fly split), pre-split transposed B planes ----
__device__ __forceinline__ void g_gemm64_bp(const float* __restrict__ A0, int ldA,
                                            const __bf16* __restrict__ Bp, int bps, int ldKb, int K,
                                            __bf16* pb, floatx16* oC){
  __bf16 *As0 = pb, *As1 = pb+2560, *As2 = pb+5120;
  __bf16 *Bs0 = pb+7680, *Bs1 = pb+10240, *Bs2 = pb+12800;
  int tid = threadIdx.x;
  int sar = tid >> 2, sako = (tid & 3)*8;
  int bn = tid & 63, bk = (tid >> 6)*8;
  int wv_ = tid >> 6, L = tid & 63, m = L & 31, half = L >> 5;
  int rA = 32*(wv_ & 1) + m, rB = 32*(wv_ >> 1) + m;
  const float* arow = A0 + (size_t)sar*ldA;
  const __bf16* brow = Bp + (size_t)bn*ldKb + bk;
  floatx16 acc;
  #pragma unroll
  for (int i = 0; i < 16; i++) acc[i] = 0.f;
  float ra[8]; bf16x8 rb[3];
  {
    float4 v0 = *(const float4*)(arow + sako);
    float4 v1 = *(const float4*)(arow + sako + 4);
    ra[0]=v0.x; ra[1]=v0.y; ra[2]=v0.z; ra[3]=v0.w; ra[4]=v1.x; ra[5]=v1.y; ra[6]=v1.z; ra[7]=v1.w;
    rb[0] = *(const bf16x8*)(brow);
    rb[1] = *(const bf16x8*)(brow + bps);
    rb[2] = *(const bf16x8*)(brow + 2*bps);
  }
  for (int k0 = 0; k0 < K; k0 += 32){
    split_store8(ra, As0, As1, As2, SW(sar, sako));
    *(bf16x8*)(Bs0 + SW(bn, bk)) = rb[0];
    *(bf16x8*)(Bs1 + SW(bn, bk)) = rb[1];
    *(bf16x8*)(Bs2 + SW(bn, bk)) = rb[2];
    __syncthreads();
    int k1 = k0 + 32;
    float ra2[8]; bf16x8 rb2[3];
    if (k1 < K){
      float4 v0 = *(const float4*)(arow + k1 + sako);
      float4 v1 = *(const float4*)(arow + k1 + sako + 4);
      ra2[0]=v0.x; ra2[1]=v0.y; ra2[2]=v0.z; ra2[3]=v0.w; ra2[4]=v1.x; ra2[5]=v1.y; ra2[6]=v1.z; ra2[7]=v1.w;
      rb2[0] = *(const bf16x8*)(brow + k1);
      rb2[1] = *(const bf16x8*)(brow + bps + k1);
      rb2[2] = *(const bf16x8*)(brow + 2*bps + k1);
    }
    #pragma unroll
    for (int kg = 0; kg < 2; kg++){
      int ko = kg*16 + half*8;
      mfma6(As0,As1,As2, Bs0,Bs1,Bs2, SW(rA,ko), SW(rB,ko), &acc);
    }
    __syncthreads();
    if (k1 < K){
      #pragma unroll
      for (int j = 0; j < 8; j++) ra[j] = ra2[j];
      rb[0]=rb2[0]; rb[1]=rb2[1]; rb[2]=rb2[2];
    }
  }
  *oC = acc;
}

// ---- 64x64-tile W1 GEMM core (K=384, pre-split transposed W1 planes, h=[a,q,a*q] synthesized) ----
__device__ __forceinline__ void g_gemm_h64(const float* __restrict__ arow, const float* __restrict__ qrow,
                                           const __bf16* __restrict__ Bp,
                                           __bf16* pb, floatx16* oC){
  __bf16 *As0 = pb, *As1 = pb+2560, *As2 = pb+5120;
  __bf16 *Bs0 = pb+7680, *Bs1 = pb+10240, *Bs2 = pb+12800;
  int tid = threadIdx.x;
  int sar = tid >> 2, sako = (tid & 3)*8;
  int bn = tid & 63, bk = (tid >> 6)*8;
  int wv_ = tid >> 6, L = tid & 63, m = L & 31, half = L >> 5;
  int rA = 32*(wv_ & 1) + m, rB = 32*(wv_ >> 1) + m;
  const __bf16* brow = Bp + (size_t)bn*384 + bk;
  auto loadA = [&](int k0, float* r){
    int seg = k0 >> 7, kl = (k0 & 127) + sako;
    if (seg == 0){
      float4 a0 = *(const float4*)(arow + kl), a1 = *(const float4*)(arow + kl + 4);
      r[0]=a0.x; r[1]=a0.y; r[2]=a0.z; r[3]=a0.w; r[4]=a1.x; r[5]=a1.y; r[6]=a1.z; r[7]=a1.w;
    } else if (seg == 1){
      float4 q0 = *(const float4*)(qrow + kl), q1 = *(const float4*)(qrow + kl + 4);
      r[0]=q0.x; r[1]=q0.y; r[2]=q0.z; r[3]=q0.w; r[4]=q1.x; r[5]=q1.y; r[6]=q1.z; r[7]=q1.w;
    } else {
      float4 a0 = *(const float4*)(arow + kl), a1 = *(const float4*)(arow + kl + 4);
      float4 q0 = *(const float4*)(qrow + kl), q1 = *(const float4*)(qrow + kl + 4);
      r[0]=a0.x*q0.x; r[1]=a0.y*q0.y; r[2]=a0.z*q0.z; r[3]=a0.w*q0.w;
      r[4]=a1.x*q1.x; r[5]=a1.y*q1.y; r[6]=a1.z*q1.z; r[7]=a1.w*q1.w;
    }
  };
  floatx16 acc;
  #pragma unroll
  for (int i = 0; i < 16; i++) acc[i] = 0.f;
  float ra[8]; bf16x8 rb[3];
  loadA(0, ra);
  rb[0] = *(const bf16x8*)(brow);
  rb[1] = *(const bf16x8*)(brow + 98304);
  rb[2] = *(const bf16x8*)(brow + 196608);
  for (int k0 = 0; k0 < 384; k0 += 32){
    split_store8(ra, As0, As1, As2, SW(sar, sako));
    *(bf16x8*)(Bs0 + SW(bn, bk)) = rb[0];
    *(bf16x8*)(Bs1 + SW(bn, bk)) = rb[1];
    *(bf16x8*)(Bs2 + SW(bn, bk)) = rb[2];
    __syncthreads();
    int k1 = k0 + 32;
    float ra2[8]; bf16x8 rb2[3];
    if (k1 < 384){
      loadA(k1, ra2);
      rb2[0] = *(const bf16x8*)(brow + k1);
      rb2[1] = *(const bf16x8*)(brow + 98304 + k1);
      rb2[2] = *(const bf16x8*)(brow + 196608 + k1);
    }
    #pragma unroll
    for (int kg = 0; kg < 2; kg++){
      int ko = kg*16 + half*8;
      mfma6(As0,As1,As2, Bs0,Bs1,Bs2, SW(rA,ko), SW(rB,ko), &acc);
    }
    __syncthreads();
    if (k1 < 384){
      #pragma unroll
      for (int j = 0; j < 8; j++) ra[j] = ra2[j];
      rb[0]=rb2[0]; rb[1]=rb2[1]; rb[2]=rb2[2];
    }
  }
  *oC = acc;
}

__device__ __forceinline__ void c_write(floatx16 accA, floatx16 accB, float* C0, int ldC, int act){
  int tid = threadIdx.x, wv_ = tid >> 6, L = tid & 63, m = L & 31, half = L >> 5;
  int rB0 = (wv_ >> 1)*32 + m, rB1 = rB0 + 64;
  int row0 = 32*(wv_ & 1) + 4*half;
  #pragma unroll
  for (int reg = 0; reg < 16; reg++){
    int row = row0 + (reg & 3) + 8*(reg >> 2);
    float va = accA[reg], vb = accB[reg];
    if (act){ va = lrelu(va); vb = lrelu(vb); }
    C0[(size_t)row*ldC + rB0] = va;
    C0[(size_t)row*ldC + rB1] = vb;
  }
}

__device__ __forceinline__ void c_write64(floatx16 acc, float* C0, int ldC, int act){
  int tid = threadIdx.x, wv_ = tid >> 6, L = tid & 63, m = L & 31, half = L >> 5;
  int col = 32*(wv_ >> 1) + m;
  int row0 = 32*(wv_ & 1) + 4*half;
  #pragma unroll
  for (int reg = 0; reg < 16; reg++){
    int row = row0 + (reg & 3) + 8*(reg >> 2);
    float v = acc[reg];
    if (act) v = lrelu(v);
    C0[(size_t)row*ldC + col] = v;
  }
}

// ---- double hop (A^T twice), A in LDS; src either global rows (ld128) or LDS (ldV); dst ld128 ----
__device__ __forceinline__ void hop2_run(const float* A, const float* VfullL, int ldV,
                                         const float* srcG, float* dstG, int dstOff,
                                         float* Vt, float* Tt, int fbeg, int fend){
  int tid = threadIdx.x;
  int tc = (tid & 31)*2, tf = (tid >> 5)*4;
  for (int f0 = fbeg; f0 < fend; f0 += 32){
    if (!VfullL){
      for (int o = tid; o < 2048; o += 256){
        int r = o >> 5, f = o & 31;
        Vt[o] = srcG[r*128 + f0 + f];
      }
      __syncthreads();
    }
    float a00,a01,a02,a03,a10,a11,a12,a13;
    a00=a01=a02=a03=a10=a11=a12=a13=0.f;
    for (int r = 0; r < 64; r++){
      float x0 = A[r*64 + tc], x1 = A[r*64 + tc + 1];
      float4 v4 = VfullL ? *(const float4*)&VfullL[r*ldV + f0 + tf]
                         : *(const float4*)&Vt[r*32 + tf];
      a00 += x0*v4.x; a01 += x0*v4.y; a02 += x0*v4.z; a03 += x0*v4.w;
      a10 += x1*v4.x; a11 += x1*v4.y; a12 += x1*v4.z; a13 += x1*v4.w;
    }
    *(float4*)&Tt[tc*32 + tf]     = make_float4(a00,a01,a02,a03);
    *(float4*)&Tt[(tc+1)*32 + tf] = make_float4(a10,a11,a12,a13);
    __syncthreads();
    a00=a01=a02=a03=a10=a11=a12=a13=0.f;
    for (int r = 0; r < 64; r++){
      float x0 = A[r*64 + tc], x1 = A[r*64 + tc + 1];
      float4 v4 = *(const float4*)&Tt[r*32 + tf];
      a00 += x0*v4.x; a01 += x0*v4.y; a02 += x0*v4.z; a03 += x0*v4.w;
      a10 += x1*v4.x; a11 += x1*v4.y; a12 += x1*v4.z; a13 += x1*v4.w;
    }
    *(float4*)(dstG + tc*128 + dstOff + f0 + tf)     = make_float4(a00,a01,a02,a03);
    *(float4*)(dstG + (tc+1)*128 + dstOff + f0 + tf) = make_float4(a10,a11,a12,a13);
    __syncthreads();
  }
}

// split+transpose store helper into 3 LDS plane slots
__device__ __forceinline__ void split_t_lds(float v, __bf16* Ls, int idx){
  __bf16 b1 = (__bf16)v;
  float r1 = v - (float)b1;
  __bf16 b2 = (__bf16)r1;
  __bf16 b3 = (__bf16)(r1 - (float)b2);
  Ls[idx] = b1; Ls[4224 + idx] = b2; Ls[8448 + idx] = b3;
}

// ===== K1: build+hop2 f-split (blk<128) || Wk-f GEMM (128..255) || W1 fold presplit (256..351)
//          || W2 presplit (352..383) || Wkg presplit (384..391)
//          || A2 zero (392..3095) || xl = x @ linW (3096..3223) =====
__global__ __launch_bounds__(256) void k_p0(const int* __restrict__ ei, const float* __restrict__ ew,
                                            const float* __restrict__ x, const float* __restrict__ Wk,
                                            const float* __restrict__ W1, const float* __restrict__ W2,
                                            const float* __restrict__ linW,
                                            float* A_g, float* M_g, float* xq, float* a_buf,
                                            __bf16* W1fp, __bf16* W2p, __bf16* Wkgp,
                                            float* xl0, float* xl1, float* outA2){
  __shared__ __align__(16) char POOL[57856];
  float* pf = (float*)POOL;
  __bf16* pb = (__bf16*)POOL;
  int blk = blockIdx.x, tid = threadIdx.x;
  if (blk < 128){
    int b = blk >> 1, fh = blk & 1;
    float* Ws = pf; float* Mc = pf + 4096; float* dv = pf + 8192;
    for (int i = tid; i < 4096; i += 256){ Ws[i] = 0.f; Mc[i] = 0.f; }
    __syncthreads();
    const int* r0 = ei + b*2048;
    const int* c0 = ei + 64*2048 + b*2048;
    const float* w0 = ew + b*2048;
    int base = b*64;
    for (int e = tid; e < 2048; e += 256){
      int r = r0[e] - base, c = c0[e] - base;
      atomicAdd(&Ws[r*64 + c], w0[e]);
      atomicAdd(&Mc[r*64 + c], 1.f);
    }
    if (tid < 64){ atomicAdd(&Ws[tid*65], 1.f); atomicAdd(&Mc[tid*65], 1.f); }
    __syncthreads();
    if (tid < 64){
      float d = 0.f;
      for (int r = 0; r < 64; r++) d += Ws[r*64 + tid];
      dv[tid] = d > 0.f ? rsqrtf(fmaxf(d, 1e-12f)) : 0.f;
    }
    __syncthreads();
    for (int i = tid; i < 4096; i += 256){
      int r = i >> 6, c = i & 63;
      float a = dv[r]*Ws[i]*dv[c];
      Ws[i] = a;
      if (fh == 0){
        A_g[b*4096 + i] = a;
        M_g[b*4096 + i] = Mc[i];
      }
    }
    __syncthreads();
    hop2_run(Ws, nullptr, 0, x + (size_t)b*8192, xq + (size_t)b*8192, 0, pf + 8256, pf + 10304,
             fh*64, fh*64 + 64);
  } else if (blk < 256){
    int idx = blk - 128, z = idx >> 6, b = idx & 63;
    floatx16 cA, cB;
    g_gemm(x + (size_t)b*8192, 128, Wk + (size_t)z*16384, 128, 128, pb, &cA, &cB);
    c_write(cA, cB, a_buf + (size_t)z*524288 + (size_t)b*8192, 128, 0);
  } else if (blk < 352){
    // W1 fold + split + transpose -> W1fp[z][plane][256 n][384 k] bf16
    __bf16* Ls = (__bf16*)POOL;
    int t = blk - 256, z = t/24, tt = t%24, k0 = (tt >> 2)*64, c0 = (tt & 3)*64;
    const float* Wz = W1 + (size_t)z*131072;
    for (int i = tid; i < 4096; i += 256){
      int kk = i >> 6, cc = i & 63, kr = k0 + kk, c = c0 + cc;
      float v;
      if (kr < 128)       v = Wz[kr*256 + c] + Wz[(kr + 256)*256 + c];
      else if (kr < 256)  v = Wz[kr*256 + c] - Wz[(kr + 128)*256 + c];
      else                v = Wz[(kr + 128)*256 + c];
      split_t_lds(v, Ls, cc*66 + kk);
    }
    __syncthreads();
    __bf16* outp = W1fp + (size_t)z*294912;
    for (int i = tid; i < 4096; i += 256){
      int cc = i >> 6, kk = i & 63;
      int o = (c0 + cc)*384 + k0 + kk;
      int li = cc*66 + kk;
      outp[o] = Ls[li];
      outp[98304 + o] = Ls[4224 + li];
      outp[196608 + o] = Ls[8448 + li];
    }
  } else if (blk < 384){
    // W2 split + transpose -> W2p[z][plane][128 n][256 k]
    __bf16* Ls = (__bf16*)POOL;
    int t = blk - 352, z = t >> 3, tt = t & 7, k0 = (tt >> 1)*64, c0 = (tt & 1)*64;
    const float* Wz = W2 + (size_t)z*32768;
    for (int i = tid; i < 4096; i += 256){
      int kk = i >> 6, cc = i & 63;
      split_t_lds(Wz[(k0 + kk)*128 + c0 + cc], Ls, cc*66 + kk);
    }
    __syncthreads();
    __bf16* outp = W2p + (size_t)z*98304;
    for (int i = tid; i < 4096; i += 256){
      int cc = i >> 6, kk = i & 63;
      int o = (c0 + cc)*256 + k0 + kk;
      int li = cc*66 + kk;
      outp[o] = Ls[li];
      outp[32768 + o] = Ls[4224 + li];
      outp[65536 + o] = Ls[8448 + li];
    }
  } else if (blk < 392){
    // Wk heads 2,3 split + transpose -> Wkgp[z][plane][128 n][128 k]
    __bf16* Ls = (__bf16*)POOL;
    int t = blk - 384, z = t >> 2, tt = t & 3, k0 = (tt >> 1)*64, c0 = (tt & 1)*64;
    const float* Wz = Wk + (size_t)(2 + z)*16384;
    for (int i = tid; i < 4096; i += 256){
      int kk = i >> 6, cc = i & 63;
      split_t_lds(Wz[(k0 + kk)*128 + c0 + cc], Ls, cc*66 + kk);
    }
    __syncthreads();
    __bf16* outp = Wkgp + (size_t)z*49152;
    for (int i = tid; i < 4096; i += 256){
      int cc = i >> 6, kk = i & 63;
      int o = (c0 + cc)*128 + k0 + kk;
      int li = cc*66 + kk;
      outp[o] = Ls[li];
      outp[16384 + o] = Ls[4224 + li];
      outp[32768 + o] = Ls[8448 + li];
    }
  } else if (blk < 3096){
    // zero-fill full A2 region (44.3 MB); nonzero blocks overwritten later by k_A2c
    float4* p = (float4*)outA2;
    int base = (blk - 392)*1024 + tid;
    #pragma unroll
    for (int i = 0; i < 4; i++) p[base + i*256] = make_float4(0.f,0.f,0.f,0.f);
  } else {
    // xl_h = x @ linW_h (2 heads x 64 batches)
    int idx = blk - 3096, z = idx >> 6, b = idx & 63;
    floatx16 cA, cB;
    g_gemm(x + (size_t)b*8192, 128, linW + (size_t)z*16384, 128, 128, pb, &cA, &cB);
    c_write(cA, cB, (z ? xl1 : xl0) + (size_t)b*8192, 128, 0);
  }
}

// ===== K2: W1 fold GEMM (512 blocks: b,z,nq) — 64x64 tiles, presplit B, fp32 h1 out =====
__global__ __launch_bounds__(256) void k_h1(const float* __restrict__ a_buf, const float* __restrict__ q0,
                                            const float* __restrict__ tgt, const __bf16* __restrict__ W1fp,
                                            float* h1){
  __shared__ __align__(16) char POOL[30720];
  __bf16* pb = (__bf16*)POOL;
  int blk = blockIdx.x, tid = threadIdx.x;
  int b = blk >> 3, z = (blk >> 2) & 1, nq = blk & 3;
  int sar = tid >> 2;
  const float* arow = a_buf + (size_t)z*524288 + ((size_t)b*64 + sar)*128;
  const float* qrow = z ? (tgt + (size_t)b*128) : (q0 + ((size_t)b*64 + sar)*128);
  floatx16 c;
  g_gemm_h64(arow, qrow, W1fp + (size_t)z*294912 + (size_t)nq*64*384, pb, &c);
  c_write64(c, h1 + (size_t)z*1048576 + (size_t)b*16384 + nq*64, 256, 1);
}

// ===== K3: W2 partial-logit GEMM (256 blocks: b,z,nh) — fp32 A, presplit B =====
__global__ __launch_bounds__(256) void k_w2p(const float* __restrict__ h1, const __bf16* __restrict__ W2p,
                                             const float* __restrict__ W3, float* __restrict__ lp){
  __shared__ __align__(16) char POOL[30720];
  __shared__ float lgp[128];
  __bf16* pb = (__bf16*)POOL;
  int blk = blockIdx.x, tid = threadIdx.x;
  int b = blk >> 2, z = (blk >> 1) & 1, nh = blk & 1;
  floatx16 c;
  g_gemm64_bp(h1 + (size_t)z*1048576 + (size_t)b*16384, 256,
              W2p + (size_t)z*98304 + (size_t)nh*64*256, 32768, 256, 256, pb, &c);
  int wv_ = tid >> 6, L = tid & 63, m = L & 31, half = L >> 5;
  int col = 32*(wv_ >> 1) + m;
  float w = W3[z*128 + nh*64 + col];
  float v[16];
  #pragma unroll
  for (int reg = 0; reg < 16; reg++) v[reg] = lrelu(c[reg])*w;
  #pragma unroll
  for (int off = 1; off < 32; off <<= 1)
    #pragma unroll
    for (int reg = 0; reg < 16; reg++) v[reg] += __shfl_xor(v[reg], off);
  if (m == 0){
    #pragma unroll
    for (int reg = 0; reg < 16; reg++) lgp[wv_*32 + half*16 + reg] = v[reg];
  }
  __syncthreads();
  if (tid < 64){
    int row = tid, rh = row >> 5, rem = row & 31;
    int hf = (rem >> 2) & 1, rg = (rem & 3) + 4*(rem >> 3);
    float p = lgp[rh*32 + hf*16 + rg] + lgp[(rh + 2)*32 + hf*16 + rg];
    lp[(z*2 + nh)*4096 + b*64 + row] = p;
  }
}

// ===== K4: edge softmax + S + y=Ew^T xl + x_c + hop2, f-split (128 blocks: b, fh) =====
__global__ __launch_bounds__(256) void k_edgehop(const float* __restrict__ M_g, const float* __restrict__ lp,
                                                 const float* __restrict__ x, const float* __restrict__ xl0g,
                                                 const float* __restrict__ xl1g, const float* __restrict__ A_g,
                                                 float* S_g, float* xcb, float* xq2){
  __shared__ __align__(16) float Mc[4096];     // multiplicity -> Ew
  __shared__ __align__(16) float xh[4096];     // x half -> x_c half (in-place)
  __shared__ __align__(16) float xl0h[4096];
  __shared__ __align__(16) float xl1h[4096];
  __shared__ __align__(16) float Ab[4096];
  __shared__ __align__(16) float Tt[2048];
  __shared__ float f1s[64], f2s[64];
  int blk = blockIdx.x, b = blk >> 1, fh = blk & 1, tid = threadIdx.x;
  int foff = fh*64;
  for (int i = tid; i < 4096; i += 256) Mc[i] = M_g[b*4096 + i];
  for (int o = tid*4; o < 4096; o += 1024){
    int r = o >> 6, f = o & 63;
    *(float4*)&xh[o]   = *(const float4*)(x    + (size_t)b*8192 + r*128 + foff + f);
    *(float4*)&xl0h[o] = *(const float4*)(xl0g + (size_t)b*8192 + r*128 + foff + f);
    *(float4*)&xl1h[o] = *(const float4*)(xl1g + (size_t)b*8192 + r*128 + foff + f);
  }
  if (tid < 128){
    int z = tid >> 6, r = tid & 63;
    float d = lp[(z*2)*4096 + b*64 + r] + lp[(z*2 + 1)*4096 + b*64 + r];
    float l = lrelu(d);
    float mx = l;
    #pragma unroll
    for (int off = 32; off; off >>= 1) mx = fmaxf(mx, __shfl_xor(mx, off));
    float e = expf(l - mx);
    float s = e;
    #pragma unroll
    for (int off = 32; off; off >>= 1) s += __shfl_xor(s, off);
    (z ? f2s : f1s)[r] = e/s;
  }
  __syncthreads();
  {
    int c = tid >> 2, sub = tid & 3;
    float m = -1e30f;
    for (int r = sub; r < 64; r += 4)
      if (Mc[r*64 + c] > 0.f) m = fmaxf(m, lrelu(f1s[c] + f2s[r]));
    m = fmaxf(m, __shfl_xor(m, 1));
    m = fmaxf(m, __shfl_xor(m, 2));
    float s = 0.f;
    for (int r = sub; r < 64; r += 4){
      float mc = Mc[r*64 + c];
      if (mc > 0.f) s += mc*expf(lrelu(f1s[c] + f2s[r]) - m);
    }
    s += __shfl_xor(s, 1);
    s += __shfl_xor(s, 2);
    for (int r = sub; r < 64; r += 4){
      float mc = Mc[r*64 + c];
      float v = 0.f;
      if (mc > 0.f) v = mc*expf(lrelu(f1s[c] + f2s[r]) - m)/s;
      Mc[r*64 + c] = v;
    }
  }
  __syncthreads();
  if (fh == 0)
    for (int i = tid; i < 4096; i += 256) S_g[b*4096 + i] = Mc[i];
  // y_h[c][f] = sum_r Ew[r][c] * xl_h[r][f]; then x_c in-place into xh
  {
    int tc = (tid & 15)*4, tf = (tid >> 4)*4;
    float a0[4][4], a1[4][4];
    #pragma unroll
    for (int i = 0; i < 4; i++)
      #pragma unroll
      for (int j = 0; j < 4; j++){ a0[i][j] = 0.f; a1[i][j] = 0.f; }
    for (int r = 0; r < 64; r++){
      float4 e4 = *(const float4*)&Mc[r*64 + tc];
      float4 p0 = *(const float4*)&xl0h[r*64 + tf];
      float4 p1 = *(const float4*)&xl1h[r*64 + tf];
      float e_[4] = {e4.x,e4.y,e4.z,e4.w};
      float p0_[4] = {p0.x,p0.y,p0.z,p0.w};
      float p1_[4] = {p1.x,p1.y,p1.z,p1.w};
      #pragma unroll
      for (int ci = 0; ci < 4; ci++)
        #pragma unroll
        for (int fj = 0; fj < 4; fj++){
          a0[ci][fj] += e_[ci]*p0_[fj];
          a1[ci][fj] += e_[ci]*p1_[fj];
        }
    }
    __syncthreads();
    #pragma unroll
    for (int ci = 0; ci < 4; ci++){
      int c = tc + ci;
      float4 xv = *(const float4*)&xh[c*64 + tf];
      float4 o;
      o.x = 0.5f*(lrelu(xv.x + a0[ci][0]) + lrelu(xv.x + a1[ci][0]));
      o.y = 0.5f*(lrelu(xv.y + a0[ci][1]) + lrelu(xv.y + a1[ci][1]));
      o.z = 0.5f*(lrelu(xv.z + a0[ci][2]) + lrelu(xv.z + a1[ci][2]));
      o.w = 0.5f*(lrelu(xv.w + a0[ci][3]) + lrelu(xv.w + a1[ci][3]));
      *(float4*)&xh[c*64 + tf] = o;
      *(float4*)(xcb + (size_t)b*8192 + c*128 + foff + tf) = o;
    }
  }
  for (int i = tid*4; i < 4096; i += 1024)
    *(float4*)&Ab[i] = *(const float4*)(A_g + b*4096 + i);
  __syncthreads();
  hop2_run(Ab, xh, 64, nullptr, xq2 + (size_t)b*8192, foff, Tt, Tt, 0, 64);
}

// ===== K5: Wk pair g (256 blocks: b,z,nh) — 64x64 tiles, presplit B =====
__global__ __launch_bounds__(256) void k_wkg(const float* __restrict__ xcb, const __bf16* __restrict__ Wkgp,
                                             float* a_buf){
  __shared__ __align__(16) char POOL[30720];
  __bf16* pb = (__bf16*)POOL;
  int blk = blockIdx.x;
  int b = blk >> 2, z = (blk >> 1) & 1, nh = blk & 1;
  floatx16 c;
  g_gemm64_bp(xcb + (size_t)b*8192, 128,
              Wkgp + (size_t)z*49152 + (size_t)nh*64*128, 16384, 128, 128, pb, &c);
  c_write64(c, a_buf + (size_t)z*524288 + (size_t)b*8192 + nh*64, 128, 0);
}

// ===== K6: pool (softmaxes from lp + bitonic top-52 + x_out) + direct A2 block writes (64 blocks) =====
__global__ __launch_bounds__(256) void k_A2c(const float* __restrict__ lp, const float* __restrict__ x,
                                             const float* __restrict__ A_g, const float* __restrict__ S_g,
                                             float* outA2, float* outX, float* outB, float* outP){
  __shared__ __align__(16) float At[64*68];
  __shared__ __align__(16) float Sp[64*56];
  __shared__ __align__(16) float Tq[64*56];
  __shared__ int pi[64];
  __shared__ float pv[64];
  int b = blockIdx.x, tid = threadIdx.x;
  if (tid < 64){
    int lane = tid;
    float f[2];
    #pragma unroll
    for (int z = 0; z < 2; z++){
      float d = lp[(z*2)*4096 + b*64 + lane] + lp[(z*2 + 1)*4096 + b*64 + lane];
      float l = lrelu(d);
      float mx = l;
      #pragma unroll
      for (int off = 32; off; off >>= 1) mx = fmaxf(mx, __shfl_xor(mx, off));
      float e = expf(l - mx);
      float sm = e;
      #pragma unroll
      for (int off = 32; off; off >>= 1) sm += __shfl_xor(sm, off);
      f[z] = e/sm;
    }
    float l = f[0] + f[1];
    float m = l;
    #pragma unroll
    for (int off = 32; off; off >>= 1) m = fmaxf(m, __shfl_xor(m, off));
    float e = expf(l - m);
    float sm = e;
    #pragma unroll
    for (int off = 32; off; off >>= 1) sm += __shfl_xor(sm, off);
    float v = e/sm;
    int idx = lane;
    #pragma unroll
    for (int k = 2; k <= 64; k <<= 1){
      #pragma unroll
      for (int j = k >> 1; j > 0; j >>= 1){
        float ov = __shfl_xor(v, j);
        int   oi = __shfl_xor(idx, j);
        bool ascBlock = (lane & k) == 0;
        bool iAmLow   = (lane & j) == 0;
        bool otherPrec = (ov > v) || (ov == v && oi < idx);
        bool take = (ascBlock == iAmLow) ? otherPrec : !otherPrec;
        if (take){ v = ov; idx = oi; }
      }
    }
    pi[lane] = idx; pv[lane] = v;
    if (lane < KK){
      outB[b*KK + lane] = (float)b;
      outP[b*KK + lane] = (float)(b*64 + idx);
    }
  }
  __syncthreads();
  for (int o = tid*4; o < KK*128; o += 1024){
    int j = o >> 7, f = o & 127;
    float4 xv = *(const float4*)(x + ((size_t)b*64 + pi[j])*128 + f);
    float sv = pv[j];
    *(float4*)(outX + (size_t)b*KK*128 + o) = make_float4(xv.x*sv, xv.y*sv, xv.z*sv, xv.w*sv);
  }
  for (int idx = tid; idx < 4096; idx += 256){
    int i = idx >> 6, k = idx & 63;
    At[k*68 + i] = A_g[b*4096 + idx];
  }
  for (int idx = tid; idx < 4096; idx += 256){
    int k = idx >> 6, t = idx & 63;
    if (t < 56) Sp[k*56 + t] = (t < KK) ? S_g[b*4096 + k*64 + pi[t]] : 0.f;
  }
  __syncthreads();
  if (tid < 224){
    int i0 = (tid/14)*4, t0 = (tid % 14)*4;
    float acc[4][4];
    #pragma unroll
    for (int a = 0; a < 4; a++)
      #pragma unroll
      for (int c = 0; c < 4; c++) acc[a][c] = 0.f;
    for (int k = 0; k < 64; k++){
      float4 a4 = *(const float4*)&At[k*68 + i0];
      float4 s4 = *(const float4*)&Sp[k*56 + t0];
      float a_[4] = {a4.x,a4.y,a4.z,a4.w};
      float s_[4] = {s4.x,s4.y,s4.z,s4.w};
      #pragma unroll
      for (int ii = 0; ii < 4; ii++)
        #pragma unroll
        for (int tt = 0; tt < 4; tt++) acc[ii][tt] += a_[ii]*s_[tt];
    }
    #pragma unroll
    for (int ii = 0; ii < 4; ii++)
      *(float4*)&Tq[(i0+ii)*56 + t0] = make_float4(acc[ii][0],acc[ii][1],acc[ii][2],acc[ii][3]);
  }
  __syncthreads();
  if (tid < 169){
    int a0 = (tid/13)*4, t0 = (tid % 13)*4;
    float acc[4][4];
    #pragma unroll
    for (int a = 0; a < 4; a++)
      #pragma unroll
      for (int c = 0; c < 4; c++) acc[a][c] = 0.f;
    for (int i = 0; i < 64; i++){
      float4 s4 = *(const float4*)&Sp[i*56 + a0];
      float4 t4 = *(const float4*)&Tq[i*56 + t0];
      float s_[4] = {s4.x,s4.y,s4.z,s4.w};
      float t_[4] = {t4.x,t4.y,t4.z,t4.w};
      #pragma unroll
      for (int aa = 0; aa < 4; aa++)
        #pragma unroll
        for (int tt = 0; tt < 4; tt++) acc[aa][tt] += s_[aa]*t_[tt];
    }
    #pragma unroll
    for (int aa = 0; aa < 4; aa++){
      int a = a0 + aa;
      float4 o;
      o.x = (a == t0    ) ? 1.f : acc[aa][0];
      o.y = (a == t0 + 1) ? 1.f : acc[aa][1];
      o.z = (a == t0 + 2) ? 1.f : acc[aa][2];
      o.w = (a == t0 + 3) ? 1.f : acc[aa][3];
      *(float4*)(outA2 + (size_t)(b*KK + a)*NKOUT + b*KK + t0) = o;
    }
  }
}

extern "C" void kernel_launch(void* const* d_in, const int* in_sizes, int n_in,
                              void* d_out, int out_size, void* d_ws, size_t ws_size,
                              hipStream_t stream){
  const float* x    = (const float*)d_in[0];
  const int*   ei   = (const int*)d_in[1];
  const float* ew   = (const float*)d_in[2];
  const float* tgt  = (const float*)d_in[3];
  const float* Wk   = (const float*)d_in[5];
  const float* W1   = (const float*)d_in[6];
  const float* W2   = (const float*)d_in[7];
  const float* W3   = (const float*)d_in[8];
  const float* linW = (const float*)d_in[9];
  float* out = (float*)d_out;

  float* wf   = (float*)d_ws;
  float* A_g  = wf;
  float* M_g  = wf + 262144;
  float* S_g  = wf + 524288;
  float* xq   = wf + 786432;
  float* xq2  = wf + 1310720;
  float* xl0  = wf + 1835008;
  float* xcb  = wf + 2359296;
  float* a_buf= wf + 2883584;              // 2 x 524288
  float* h1   = wf + 3932160;              // 2 x 1048576 fp32
  float* lp   = wf + 6029312;              // 4 x 4096 partial logits
  float* xl1  = wf + 6045696;              // 524288
  __bf16* W1fp = (__bf16*)(wf + 6569984);  // 4 z x 3 planes x 256 n x 384 k bf16
  __bf16* W2p  = (__bf16*)(wf + 7159808);  // 4 z x 3 planes x 128 n x 256 k bf16
  __bf16* Wkgp = (__bf16*)(wf + 7356416);  // 2 z x 3 planes x 128 n x 128 k bf16

  float* outX  = out;
  float* outA2 = out + 425984;
  float* outB  = out + 425984 + 11075584;
  float* outP  = outB + NKOUT;

  // pair f (+ weight pre-split/transpose + A2 zero-fill + xl precompute in spare blocks)
  k_p0<<<dim3(3224), dim3(256), 0, stream>>>(ei, ew, x, Wk, W1, W2, linW, A_g, M_g, xq, a_buf,
                                             W1fp, W2p, Wkgp, xl0, xl1, outA2);
  k_h1<<<dim3(512), dim3(256), 0, stream>>>(a_buf, xq, tgt, W1fp, h1);
  k_w2p<<<dim3(256), dim3(256), 0, stream>>>(h1, W2p, W3, lp);
  // fused edge softmax + S + y=Ew^T xl + x_c + hop2 (f-split, 128 blocks)
  k_edgehop<<<dim3(128), dim3(256), 0, stream>>>(M_g, lp, x, xl0, xl1, A_g, S_g, xcb, xq2);
  // pair g
  k_wkg<<<dim3(256), dim3(256), 0, stream>>>(xcb, Wkgp, a_buf);
  k_h1<<<dim3(512), dim3(256), 0, stream>>>(a_buf, xq2, tgt, W1fp + 2*294912, h1);
  k_w2p<<<dim3(256), dim3(256), 0, stream>>>(h1, W2p + 2*98304, W3 + 2*128, lp);
  // pool + direct A2 block writes
  k_A2c<<<dim3(64), dim3(256), 0, stream>>>(lp, x, A_g, S_g, outA2, outX, outB, outP);
}